// Round 6
// baseline (142.334 us; speedup 1.0000x reference)
//
#include <hip/hip_runtime.h>
#include <hip/hip_bf16.h>
#include <math.h>

#define BN 8192
#define DK 128
#define NSPLIT 32
#define JR (BN / NSPLIT)   // 256
#define NJS (JR / 64)      // 4
#define MARGIN_F 1.0f
#define I32MIN (-2147483647 - 1)
#define I32MAX 2147483647

// ---------------- workspace layout (float-offsets from d_ws) ----------------
// Eb   : [0, 524288)  bf16 8192x128 (as 2-byte elems)   = 2MB
// sq64 : f32, 64 * sum(x^2)
// posP : i32 [NSPLIT][BN] packed (key<<13 | (8191-j))
// negP : i32 [NSPLIT][BN] packed (key<<13 | j)
// loss : f32 [BN]
#define OFF_SQ   524288
#define OFF_POSP (OFF_SQ + BN)
#define OFF_NEGP (OFF_POSP + NSPLIT * BN)
#define OFF_LOSS (OFF_NEGP + NSPLIT * BN)

typedef __attribute__((ext_vector_type(8))) short bf16x8;
typedef __attribute__((ext_vector_type(4))) float f32x4;

__device__ __forceinline__ unsigned short f2bf(float f) {
    __hip_bfloat16 h = __float2bfloat16(f);
    return *reinterpret_cast<unsigned short*>(&h);
}
__device__ __forceinline__ int imax(int a, int b) { return a > b ? a : b; }
__device__ __forceinline__ int imin(int a, int b) { return a < b ? a : b; }

// ---------------- prep: bf16 table + 64*rowsq, one wave per row ----------------
__global__ __launch_bounds__(256) void k_prep(const float* __restrict__ emb,
                                              unsigned short* __restrict__ Eb,
                                              float* __restrict__ sq64) {
    int row  = blockIdx.x * 4 + (threadIdx.x >> 6);
    int lane = threadIdx.x & 63;
    float2 v = ((const float2*)(emb + (size_t)row * DK))[lane];
    ushort2 o; o.x = f2bf(v.x); o.y = f2bf(v.y);
    ((ushort2*)(Eb + (size_t)row * DK))[lane] = o;
    float s = v.x * v.x + v.y * v.y;
    #pragma unroll
    for (int m = 32; m; m >>= 1) s += __shfl_xor(s, m);
    if (lane == 0) sq64[row] = 64.0f * s;
}

// ---------------- fused MFMA Gram + batch-hard mining (no LDS, no barriers) ---
// 4096 independent waves: 128 i-tiles (64 rows) x 32 j-splits (256 cols).
// 1024 blocks = 4 blocks/CU = 4 waves/SIMD (TLP hides L2 latency).
// A-frags in regs (scaled by -128 via bf16 bit trick); B straight from L2;
// acc initialized to 64*sq_j so acc == 64*(sq_j - 2 dot) == 64*mining-key.
// Packed-i32 mining: pos = max((key<<13)|(8191-j)), neg = min((key<<13)|j)
// -> ties resolve to LOWEST j for both, matching JAX argmax/argmin.
__global__ __launch_bounds__(256, 4)
void k_mine2(const unsigned short* __restrict__ Eb,
             const float* __restrict__ sq64,
             const int* __restrict__ tgt,
             int* __restrict__ posP, int* __restrict__ negP) {
    const int w  = threadIdx.x >> 6;
    const int l  = threadIdx.x & 63;
    const int gw = blockIdx.x * 4 + w;
    const int itile = gw >> 5;            // 0..127
    const int split = gw & 31;            // 0..31
    const int i0 = itile * 64;
    const int jb = split * JR;
    const int lh = l >> 4;
    const int tx = l & 15;
    const char* EbB = (const char*)Eb;

    // hoist A fragments: row i0+mi*16+tx, bytes [ks*64 + lh*16)
    bf16x8 A[4][4];
    #pragma unroll
    for (int mi = 0; mi < 4; ++mi) {
        const char* rp = EbB + (size_t)(i0 + mi * 16 + tx) * 256 + lh * 16;
        #pragma unroll
        for (int ks = 0; ks < 4; ++ks)
            A[mi][ks] = *(const bf16x8*)(rp + ks * 64);
    }
    // scale A by -128 in-register: bf16 exponent += 7, sign flip. (exact)
    #pragma unroll
    for (int mi = 0; mi < 4; ++mi)
        #pragma unroll
        for (int ks = 0; ks < 4; ++ks) {
            int4& q = *reinterpret_cast<int4*>(&A[mi][ks]);
            q.x = (q.x + 0x03800380) ^ 0x80008000;
            q.y = (q.y + 0x03800380) ^ 0x80008000;
            q.z = (q.z + 0x03800380) ^ 0x80008000;
            q.w = (q.w + 0x03800380) ^ 0x80008000;
        }

    // per-lane i-row targets: rows i0 + mi*16 + lh*4 + v
    int ti_[16];
    #pragma unroll
    for (int mi = 0; mi < 4; ++mi) {
        int4 q = *(const int4*)(tgt + i0 + mi * 16 + lh * 4);
        ti_[mi * 4 + 0] = q.x; ti_[mi * 4 + 1] = q.y;
        ti_[mi * 4 + 2] = q.z; ti_[mi * 4 + 3] = q.w;
    }

    int pp[16], nn[16];
    #pragma unroll
    for (int r = 0; r < 16; ++r) { pp[r] = I32MIN; nn[r] = I32MAX; }

    for (int js = 0; js < NJS; ++js) {
        const int j0 = jb + js * 64;
        int jn[4], jc[4], tj[4]; float sqj[4];
        #pragma unroll
        for (int ni = 0; ni < 4; ++ni) {
            int j = j0 + ni * 16 + tx;
            jn[ni] = j; jc[ni] = 8191 - j;
            sqj[ni] = sq64[j]; tj[ni] = tgt[j];
        }

        f32x4 acc[4][4];
        #pragma unroll
        for (int mi = 0; mi < 4; ++mi)
            #pragma unroll
            for (int ni = 0; ni < 4; ++ni) {
                f32x4 a0 = {sqj[ni], sqj[ni], sqj[ni], sqj[ni]};
                acc[mi][ni] = a0;
            }

        #pragma unroll
        for (int ks = 0; ks < 4; ++ks) {
            bf16x8 Bf[4];
            #pragma unroll
            for (int ni = 0; ni < 4; ++ni)
                Bf[ni] = *(const bf16x8*)(EbB + (size_t)jn[ni] * 256 + ks * 64 + lh * 16);
            #pragma unroll
            for (int mi = 0; mi < 4; ++mi)
                #pragma unroll
                for (int ni = 0; ni < 4; ++ni)
                    acc[mi][ni] = __builtin_amdgcn_mfma_f32_16x16x32_bf16(
                        A[mi][ks], Bf[ni], acc[mi][ni], 0, 0, 0);
        }

        // mining epilogue: acc == 64*(sq_j - 2 dot)
        #pragma unroll
        for (int mi = 0; mi < 4; ++mi) {
            #pragma unroll
            for (int v = 0; v < 4; ++v) {
                const int r = mi * 4 + v;
                const int t_i = ti_[r];
                #pragma unroll
                for (int pr = 0; pr < 2; ++pr) {
                    const int n0 = 2 * pr, n1 = 2 * pr + 1;
                    int k0 = (int)acc[mi][n0][v];
                    int k1 = (int)acc[mi][n1][v];
                    int p0 = (int)(((unsigned)k0 << 13) | (unsigned)jc[n0]);
                    int p1 = (int)(((unsigned)k1 << 13) | (unsigned)jc[n1]);
                    int q0 = (int)(((unsigned)k0 << 13) | (unsigned)jn[n0]);
                    int q1 = (int)(((unsigned)k1 << 13) | (unsigned)jn[n1]);
                    bool s0 = (tj[n0] == t_i);
                    bool s1 = (tj[n1] == t_i);
                    int a0 = s0 ? p0 : I32MIN;
                    int a1 = s1 ? p1 : I32MIN;
                    int b0 = s0 ? I32MAX : q0;
                    int b1 = s1 ? I32MAX : q1;
                    pp[r] = imax(imax(pp[r], a0), a1);   // -> v_max3_i32
                    nn[r] = imin(imin(nn[r], b0), b1);   // -> v_min3_i32
                }
            }
        }
    }

    // reduce across the 16 tx lanes (packed compare: ties -> lowest j)
    #pragma unroll
    for (int r = 0; r < 16; ++r) {
        int p = pp[r], n = nn[r];
        #pragma unroll
        for (int m = 1; m < 16; m <<= 1) {
            p = imax(p, __shfl_xor(p, m));
            n = imin(n, __shfl_xor(n, m));
        }
        if (tx == 0) {
            int row = i0 + (r >> 2) * 16 + lh * 4 + (r & 3);
            posP[split * BN + row] = p;
            negP[split * BN + row] = n;
        }
    }
}

// ---------------- combine splits + exact f32 dp/dn + per-row loss ----------------
__global__ __launch_bounds__(256) void k_fin(const float* __restrict__ emb,
                                             const int* __restrict__ posP,
                                             const int* __restrict__ negP,
                                             float* __restrict__ loss) {
    int row  = blockIdx.x * 4 + (threadIdx.x >> 6);
    int lane = threadIdx.x & 63;

    int p = I32MIN, n = I32MAX;
    if (lane < NSPLIT) {
        p = posP[lane * BN + row];
        n = negP[lane * BN + row];
    }
    #pragma unroll
    for (int m = 1; m < NSPLIT; m <<= 1) {
        p = imax(p, __shfl_xor(p, m));
        n = imin(n, __shfl_xor(n, m));
    }
    p = __shfl(p, 0); n = __shfl(n, 0);
    int bpi = 8191 - (p & 8191), bni = n & 8191;

    float2 a  = ((const float2*)(emb + (size_t)row * DK))[lane];
    float2 pv = ((const float2*)(emb + (size_t)bpi * DK))[lane];
    float2 nv = ((const float2*)(emb + (size_t)bni * DK))[lane];
    float dp = (a.x - pv.x) * (a.x - pv.x) + (a.y - pv.y) * (a.y - pv.y);
    float dn = (a.x - nv.x) * (a.x - nv.x) + (a.y - nv.y) * (a.y - nv.y);
    #pragma unroll
    for (int m = 32; m; m >>= 1) {
        dp += __shfl_xor(dp, m);
        dn += __shfl_xor(dn, m);
    }
    if (lane == 0) {
        float lo = sqrtf(dp) - sqrtf(dn) + MARGIN_F;
        loss[row] = lo > 0.f ? lo : 0.f;
    }
}

// ---------------- mean over BN losses ----------------
__global__ __launch_bounds__(256) void k_mean(const float* __restrict__ loss,
                                              float* __restrict__ out) {
    int tid = threadIdx.x;
    float s = 0.f;
    for (int q = tid; q < BN; q += 256) s += loss[q];
    #pragma unroll
    for (int m = 32; m; m >>= 1) s += __shfl_xor(s, m);
    __shared__ float wsum[4];
    if ((tid & 63) == 0) wsum[tid >> 6] = s;
    __syncthreads();
    if (tid == 0) out[0] = (wsum[0] + wsum[1] + wsum[2] + wsum[3]) * (1.0f / BN);
}

extern "C" void kernel_launch(void* const* d_in, const int* in_sizes, int n_in,
                              void* d_out, int out_size, void* d_ws, size_t ws_size,
                              hipStream_t stream) {
    const float* emb = (const float*)d_in[0];
    const int*   tgt = (const int*)d_in[1];
    float* out = (float*)d_out;

    float* wsf = (float*)d_ws;
    unsigned short* Eb = (unsigned short*)wsf;
    float* sq64 = wsf + OFF_SQ;
    int*   posP = (int*)(wsf + OFF_POSP);
    int*   negP = (int*)(wsf + OFF_NEGP);
    float* loss = wsf + OFF_LOSS;

    k_prep<<<BN / 4, 256, 0, stream>>>(emb, Eb, sq64);
    k_mine2<<<(BN / 64) * NSPLIT / 4, 256, 0, stream>>>(Eb, sq64, tgt, posP, negP);
    k_fin<<<BN / 4, 256, 0, stream>>>(emb, posP, negP, loss);
    k_mean<<<1, 256, 0, stream>>>(loss, out);
}

// Round 7
// 73.278 us; speedup vs baseline: 1.9424x; 1.9424x over previous
//
#include <hip/hip_runtime.h>
#include <hip/hip_bf16.h>
#include <math.h>

#define BN 8192
#define DK 128
#define NSPLIT 32
#define JR (BN / NSPLIT)   // 256
#define NJS (JR / 64)      // 4
#define MARGIN_F 1.0f
#define I32MIN (-2147483647 - 1)
#define I32MAX 2147483647

// ---------------- workspace layout (float-offsets from d_ws) ----------------
#define OFF_SQ   524288
#define OFF_POSP (OFF_SQ + BN)
#define OFF_NEGP (OFF_POSP + NSPLIT * BN)
#define OFF_LOSS (OFF_NEGP + NSPLIT * BN)

typedef __attribute__((ext_vector_type(8))) short bf16x8;
typedef __attribute__((ext_vector_type(4))) float f32x4;

__device__ __forceinline__ unsigned short f2bf(float f) {
    __hip_bfloat16 h = __float2bfloat16(f);
    return *reinterpret_cast<unsigned short*>(&h);
}
__device__ __forceinline__ int imax(int a, int b) { return a > b ? a : b; }
__device__ __forceinline__ int imin(int a, int b) { return a < b ? a : b; }

// ---------------- prep: bf16 table + 64*rowsq, one wave per row ----------------
__global__ __launch_bounds__(256) void k_prep(const float* __restrict__ emb,
                                              unsigned short* __restrict__ Eb,
                                              float* __restrict__ sq64) {
    int row  = blockIdx.x * 4 + (threadIdx.x >> 6);
    int lane = threadIdx.x & 63;
    float2 v = ((const float2*)(emb + (size_t)row * DK))[lane];
    ushort2 o; o.x = f2bf(v.x); o.y = f2bf(v.y);
    ((ushort2*)(Eb + (size_t)row * DK))[lane] = o;
    float s = v.x * v.x + v.y * v.y;
    #pragma unroll
    for (int m = 32; m; m >>= 1) s += __shfl_xor(s, m);
    if (lane == 0) sq64[row] = 64.0f * s;
}

// ---------------- fused MFMA Gram + batch-hard mining (no LDS, no barriers) ---
// 4096 independent waves: 128 i-tiles (64 rows) x 32 j-splits (256 cols).
// 1024 blocks = 4 blocks/CU; VGPR ~124 <= 128 -> 4 waves/SIMD co-resident.
// NOTE: __launch_bounds__(256,2), NOT (256,4): the 4-min-waves variant forced
// a 64-VGPR budget and spilled everything to scratch (round-6 regression:
// FETCH 245MB, WRITE 197MB of spill traffic). (256,2) gives natural 124 VGPR,
// which the HW still co-schedules at 4 waves/SIMD (occupancy steps at 128).
__global__ __launch_bounds__(256, 2)
void k_mine2(const unsigned short* __restrict__ Eb,
             const float* __restrict__ sq64,
             const int* __restrict__ tgt,
             int* __restrict__ posP, int* __restrict__ negP) {
    const int w  = threadIdx.x >> 6;
    const int l  = threadIdx.x & 63;
    const int gw = blockIdx.x * 4 + w;
    const int itile = gw >> 5;            // 0..127
    const int split = gw & 31;            // 0..31
    const int i0 = itile * 64;
    const int jb = split * JR;
    const int lh = l >> 4;
    const int tx = l & 15;
    const char* EbB = (const char*)Eb;

    // hoist A fragments: row i0+mi*16+tx, bytes [ks*64 + lh*16)
    bf16x8 A[4][4];
    #pragma unroll
    for (int mi = 0; mi < 4; ++mi) {
        const char* rp = EbB + (size_t)(i0 + mi * 16 + tx) * 256 + lh * 16;
        #pragma unroll
        for (int ks = 0; ks < 4; ++ks)
            A[mi][ks] = *(const bf16x8*)(rp + ks * 64);
    }
    // scale A by -128 in-register: bf16 exponent += 7, sign flip. (exact)
    #pragma unroll
    for (int mi = 0; mi < 4; ++mi)
        #pragma unroll
        for (int ks = 0; ks < 4; ++ks) {
            int4& q = *reinterpret_cast<int4*>(&A[mi][ks]);
            q.x = (q.x + 0x03800380) ^ 0x80008000;
            q.y = (q.y + 0x03800380) ^ 0x80008000;
            q.z = (q.z + 0x03800380) ^ 0x80008000;
            q.w = (q.w + 0x03800380) ^ 0x80008000;
        }

    // per-lane i-row targets: rows i0 + mi*16 + lh*4 + v
    int ti_[16];
    #pragma unroll
    for (int mi = 0; mi < 4; ++mi) {
        int4 q = *(const int4*)(tgt + i0 + mi * 16 + lh * 4);
        ti_[mi * 4 + 0] = q.x; ti_[mi * 4 + 1] = q.y;
        ti_[mi * 4 + 2] = q.z; ti_[mi * 4 + 3] = q.w;
    }

    int pp[16], nn[16];
    #pragma unroll
    for (int r = 0; r < 16; ++r) { pp[r] = I32MIN; nn[r] = I32MAX; }

    for (int js = 0; js < NJS; ++js) {
        const int j0 = jb + js * 64;
        int jn[4], jc[4], tj[4]; float sqj[4];
        #pragma unroll
        for (int ni = 0; ni < 4; ++ni) {
            int j = j0 + ni * 16 + tx;
            jn[ni] = j; jc[ni] = 8191 - j;
            sqj[ni] = sq64[j]; tj[ni] = tgt[j];
        }

        f32x4 acc[4][4];
        #pragma unroll
        for (int mi = 0; mi < 4; ++mi)
            #pragma unroll
            for (int ni = 0; ni < 4; ++ni) {
                f32x4 a0 = {sqj[ni], sqj[ni], sqj[ni], sqj[ni]};
                acc[mi][ni] = a0;
            }

        #pragma unroll
        for (int ks = 0; ks < 4; ++ks) {
            bf16x8 Bf[4];
            #pragma unroll
            for (int ni = 0; ni < 4; ++ni)
                Bf[ni] = *(const bf16x8*)(EbB + (size_t)jn[ni] * 256 + ks * 64 + lh * 16);
            #pragma unroll
            for (int mi = 0; mi < 4; ++mi)
                #pragma unroll
                for (int ni = 0; ni < 4; ++ni)
                    acc[mi][ni] = __builtin_amdgcn_mfma_f32_16x16x32_bf16(
                        A[mi][ks], Bf[ni], acc[mi][ni], 0, 0, 0);
        }

        // mining epilogue: acc == 64*(sq_j - 2 dot)
        #pragma unroll
        for (int mi = 0; mi < 4; ++mi) {
            #pragma unroll
            for (int v = 0; v < 4; ++v) {
                const int r = mi * 4 + v;
                const int t_i = ti_[r];
                #pragma unroll
                for (int pr = 0; pr < 2; ++pr) {
                    const int n0 = 2 * pr, n1 = 2 * pr + 1;
                    int k0 = (int)acc[mi][n0][v];
                    int k1 = (int)acc[mi][n1][v];
                    int p0 = (int)(((unsigned)k0 << 13) | (unsigned)jc[n0]);
                    int p1 = (int)(((unsigned)k1 << 13) | (unsigned)jc[n1]);
                    int q0 = (int)(((unsigned)k0 << 13) | (unsigned)jn[n0]);
                    int q1 = (int)(((unsigned)k1 << 13) | (unsigned)jn[n1]);
                    bool s0 = (tj[n0] == t_i);
                    bool s1 = (tj[n1] == t_i);
                    int a0 = s0 ? p0 : I32MIN;
                    int a1 = s1 ? p1 : I32MIN;
                    int b0 = s0 ? I32MAX : q0;
                    int b1 = s1 ? I32MAX : q1;
                    pp[r] = imax(imax(pp[r], a0), a1);   // -> v_max3_i32
                    nn[r] = imin(imin(nn[r], b0), b1);   // -> v_min3_i32
                }
            }
        }
    }

    // reduce across the 16 tx lanes (packed compare: ties -> lowest j)
    #pragma unroll
    for (int r = 0; r < 16; ++r) {
        int p = pp[r], n = nn[r];
        #pragma unroll
        for (int m = 1; m < 16; m <<= 1) {
            p = imax(p, __shfl_xor(p, m));
            n = imin(n, __shfl_xor(n, m));
        }
        if (tx == 0) {
            int row = i0 + (r >> 2) * 16 + lh * 4 + (r & 3);
            posP[split * BN + row] = p;
            negP[split * BN + row] = n;
        }
    }
}

// ---------------- combine splits + exact f32 dp/dn + per-row loss ----------------
__global__ __launch_bounds__(256) void k_fin(const float* __restrict__ emb,
                                             const int* __restrict__ posP,
                                             const int* __restrict__ negP,
                                             float* __restrict__ loss) {
    int row  = blockIdx.x * 4 + (threadIdx.x >> 6);
    int lane = threadIdx.x & 63;

    int p = I32MIN, n = I32MAX;
    if (lane < NSPLIT) {
        p = posP[lane * BN + row];
        n = negP[lane * BN + row];
    }
    #pragma unroll
    for (int m = 1; m < NSPLIT; m <<= 1) {
        p = imax(p, __shfl_xor(p, m));
        n = imin(n, __shfl_xor(n, m));
    }
    p = __shfl(p, 0); n = __shfl(n, 0);
    int bpi = 8191 - (p & 8191), bni = n & 8191;

    float2 a  = ((const float2*)(emb + (size_t)row * DK))[lane];
    float2 pv = ((const float2*)(emb + (size_t)bpi * DK))[lane];
    float2 nv = ((const float2*)(emb + (size_t)bni * DK))[lane];
    float dp = (a.x - pv.x) * (a.x - pv.x) + (a.y - pv.y) * (a.y - pv.y);
    float dn = (a.x - nv.x) * (a.x - nv.x) + (a.y - nv.y) * (a.y - nv.y);
    #pragma unroll
    for (int m = 32; m; m >>= 1) {
        dp += __shfl_xor(dp, m);
        dn += __shfl_xor(dn, m);
    }
    if (lane == 0) {
        float lo = sqrtf(dp) - sqrtf(dn) + MARGIN_F;
        loss[row] = lo > 0.f ? lo : 0.f;
    }
}

// ---------------- mean over BN losses ----------------
__global__ __launch_bounds__(256) void k_mean(const float* __restrict__ loss,
                                              float* __restrict__ out) {
    int tid = threadIdx.x;
    float s = 0.f;
    for (int q = tid; q < BN; q += 256) s += loss[q];
    #pragma unroll
    for (int m = 32; m; m >>= 1) s += __shfl_xor(s, m);
    __shared__ float wsum[4];
    if ((tid & 63) == 0) wsum[tid >> 6] = s;
    __syncthreads();
    if (tid == 0) out[0] = (wsum[0] + wsum[1] + wsum[2] + wsum[3]) * (1.0f / BN);
}

extern "C" void kernel_launch(void* const* d_in, const int* in_sizes, int n_in,
                              void* d_out, int out_size, void* d_ws, size_t ws_size,
                              hipStream_t stream) {
    const float* emb = (const float*)d_in[0];
    const int*   tgt = (const int*)d_in[1];
    float* out = (float*)d_out;

    float* wsf = (float*)d_ws;
    unsigned short* Eb = (unsigned short*)wsf;
    float* sq64 = wsf + OFF_SQ;
    int*   posP = (int*)(wsf + OFF_POSP);
    int*   negP = (int*)(wsf + OFF_NEGP);
    float* loss = wsf + OFF_LOSS;

    k_prep<<<BN / 4, 256, 0, stream>>>(emb, Eb, sq64);
    k_mine2<<<(BN / 64) * NSPLIT / 4, 256, 0, stream>>>(Eb, sq64, tgt, posP, negP);
    k_fin<<<BN / 4, 256, 0, stream>>>(emb, posP, negP, loss);
    k_mean<<<1, 256, 0, stream>>>(loss, out);
}